// Round 8
// baseline (534.235 us; speedup 1.0000x reference)
//
#include <hip/hip_runtime.h>
#include <cstdint>
#include <cstddef>

#define N_NODESC 50000
#define N_PAD    50048   // 782 * 64
#define N_EDGESC 600000
#define N_GRAPHSC 64
#define D_HIDC   128
#define D_LATC   64
#define D_G      640     // h(128) + mean,mx,mn,std (4*128)
#define D_WROW   1664    // transposed W row length (13*128)

typedef unsigned short u16;
typedef unsigned int   u32;

typedef _Float16 f16x8 __attribute__((ext_vector_type(8)));
typedef _Float16 f16x2 __attribute__((ext_vector_type(2)));
typedef float    f32x4 __attribute__((ext_vector_type(4)));
typedef float    f32x2 __attribute__((ext_vector_type(2)));

__device__ __forceinline__ u16 f2h(float f) {
    return __builtin_bit_cast(u16, (_Float16)f);
}
__device__ __forceinline__ float h2f(u16 u) {
    return (float)__builtin_bit_cast(_Float16, u);
}

__device__ __forceinline__ void gll16(void* lds, const void* g) {
    // async global->LDS, 16B per lane; HW dest = wave-uniform base + lane*16
    __builtin_amdgcn_global_load_lds(
        (const __attribute__((address_space(1))) void*)g,
        (__attribute__((address_space(3))) void*)lds, 16, 0, 0);
}

// ---------------- fused setup ----------------
// block ranges: [0,ZB) zero | [ZB,ZB+12500) x2h | next 2496 wconv | last goff
__global__ void __launch_bounds__(256) k_setup(
        const float* __restrict__ x, const float* __restrict__ W0,
        const float* __restrict__ W1, const float* __restrict__ W2,
        const int* __restrict__ batch,
        u16* __restrict__ h, u16* __restrict__ Wt,
        int* __restrict__ zero_base, int nz, int ZB, int* __restrict__ goff) {
    int b = blockIdx.x;
    int t = threadIdx.x;
    if (b < ZB) {
        int i = b * 256 + t;
        if (i < nz) zero_base[i] = 0;
        return;
    }
    b -= ZB;
    if (b < 12500) {                       // x -> fp16 (2 elems/thread)
        int i = b * 256 + t;
        float2 v = ((const float2*)x)[i];
        ((u32*)h)[i] = (u32)f2h(v.x) | ((u32)f2h(v.y) << 16);
        return;
    }
    b -= 12500;
    if (b < 2496) {                        // W transpose+cast: [1664][128] -> [128][1664]
        int which = b / 832;
        int i = (b % 832) * 256 + t;
        const float* W = (which == 0) ? W0 : (which == 1) ? W1 : W2;
        int k = i / D_HIDC, j = i % D_HIDC;
        Wt[(size_t)which * D_WROW * D_HIDC + (size_t)j * D_WROW + k] = f2h(W[i]);
        return;
    }
    // goff via binary search over sorted batch
    int g = t;
    if (g <= N_GRAPHSC) {
        int lo = 0, hi = N_NODESC;
        while (lo < hi) {
            int mid = (lo + hi) >> 1;
            if (batch[mid] < g) lo = mid + 1; else hi = mid;
        }
        goff[g] = lo;
    }
}

__global__ void k_count(const int* __restrict__ dst, int* __restrict__ deg) {
    int e = blockIdx.x * 256 + threadIdx.x;
    if (e < N_EDGESC) atomicAdd(&deg[dst[e]], 1);
}

// single-block scan of deg -> row_off, plus delta = mean(log(deg+1))
__global__ void __launch_bounds__(1024) k_scan_one(
        const int* __restrict__ deg, int* __restrict__ row_off,
        float* __restrict__ delta_p) {
    __shared__ int ps[1024];
    __shared__ float ls[1024];
    const int PER = 49;   // 1024*49 >= 50000
    int t = threadIdx.x;
    int base = t * PER;
    int s = 0; float lf = 0.f;
    for (int i = 0; i < PER; i++) {
        int idx = base + i;
        if (idx < N_NODESC) {
            int d = deg[idx];
            s += d;
            lf += logf((float)d + 1.0f);
        }
    }
    ps[t] = s; ls[t] = lf;
    __syncthreads();
    for (int o = 1; o < 1024; o <<= 1) {
        int add = (t >= o) ? ps[t - o] : 0;
        __syncthreads();
        ps[t] += add;
        __syncthreads();
    }
    for (int o = 512; o > 0; o >>= 1) {
        if (t < o) ls[t] += ls[t + o];
        __syncthreads();
    }
    if (t == 0) delta_p[0] = ls[0] * (1.0f / (float)N_NODESC);
    int run = ps[t] - s;   // exclusive
    for (int i = 0; i < PER; i++) {
        int idx = base + i;
        if (idx < N_NODESC) { row_off[idx] = run; run += deg[idx]; }
    }
    if (t == 1023) row_off[N_NODESC] = N_EDGESC;
}

__global__ void k_fill_csr(const int* __restrict__ src, const int* __restrict__ dst,
                           const int* __restrict__ row_off, int* __restrict__ cursor,
                           int* __restrict__ csr_src) {
    int e = blockIdx.x * 256 + threadIdx.x;
    if (e < N_EDGESC) {
        int d = dst[e];
        int pos = row_off[d] + atomicAdd(&cursor[d], 1);
        csr_src[pos] = src[e];
    }
}

// ---------------- per-layer kernels ----------------

// one wave per node; two half-waves over alternate edges; packed fp16 min/max,
// packed f32 sum/sq. writes G[n] = [h, mean, max, min, std] fp16
__global__ void __launch_bounds__(256) k_aggregate(
        const u16* __restrict__ h, const int* __restrict__ row_off,
        const int* __restrict__ csr_src, u16* __restrict__ G) {
    int n = blockIdx.x * 4 + (threadIdx.x >> 6);
    if (n >= N_NODESC) return;
    int lane = threadIdx.x & 63;
    int half = lane >> 5, l32 = lane & 31;
    int c4 = 4 * l32;
    int beg = row_off[n], end = row_off[n + 1];
    f32x2 s01 = {0.f, 0.f}, s23 = {0.f, 0.f};
    f32x2 q01 = {0.f, 0.f}, q23 = {0.f, 0.f};
    const _Float16 NEG = (_Float16)(-65504.0f), POS = (_Float16)(65504.0f);
    f16x2 mx01 = {NEG, NEG}, mx23 = {NEG, NEG};
    f16x2 mn01 = {POS, POS}, mn23 = {POS, POS};

    #define PROC(u) { \
        f16x2 p01 = __builtin_bit_cast(f16x2, (u).x); \
        f16x2 p23 = __builtin_bit_cast(f16x2, (u).y); \
        f32x2 c01 = __builtin_convertvector(p01, f32x2); \
        f32x2 c23 = __builtin_convertvector(p23, f32x2); \
        s01 += c01; s23 += c23; \
        q01 += c01 * c01; q23 += c23 * c23; \
        mx01 = __builtin_elementwise_max(mx01, p01); \
        mx23 = __builtin_elementwise_max(mx23, p23); \
        mn01 = __builtin_elementwise_min(mn01, p01); \
        mn23 = __builtin_elementwise_min(mn23, p23); }

    int i = beg + half;
    for (; i + 2 < end; i += 4) {
        int ea = csr_src[i], eb = csr_src[i + 2];
        uint2 ua = *(const uint2*)(h + (size_t)ea * D_HIDC + c4);
        uint2 ub = *(const uint2*)(h + (size_t)eb * D_HIDC + c4);
        PROC(ua);
        PROC(ub);
    }
    if (i < end) {
        int ea = csr_src[i];
        uint2 ua = *(const uint2*)(h + (size_t)ea * D_HIDC + c4);
        PROC(ua);
    }
    #undef PROC

    // merge half-waves
    s01.x += __shfl_xor(s01.x, 32); s01.y += __shfl_xor(s01.y, 32);
    s23.x += __shfl_xor(s23.x, 32); s23.y += __shfl_xor(s23.y, 32);
    q01.x += __shfl_xor(q01.x, 32); q01.y += __shfl_xor(q01.y, 32);
    q23.x += __shfl_xor(q23.x, 32); q23.y += __shfl_xor(q23.y, 32);
    mx01 = __builtin_elementwise_max(mx01,
        __builtin_bit_cast(f16x2, __shfl_xor(__builtin_bit_cast(int, mx01), 32)));
    mx23 = __builtin_elementwise_max(mx23,
        __builtin_bit_cast(f16x2, __shfl_xor(__builtin_bit_cast(int, mx23), 32)));
    mn01 = __builtin_elementwise_min(mn01,
        __builtin_bit_cast(f16x2, __shfl_xor(__builtin_bit_cast(int, mn01), 32)));
    mn23 = __builtin_elementwise_min(mn23,
        __builtin_bit_cast(f16x2, __shfl_xor(__builtin_bit_cast(int, mn23), 32)));

    int d = end - beg;
    float inv = 1.0f / fmaxf((float)d, 1.0f);
    float me0 = s01.x * inv, me1 = s01.y * inv, me2 = s23.x * inv, me3 = s23.y * inv;
    float sd0 = sqrtf(fmaxf(q01.x * inv - me0 * me0, 0.0f) + 1e-5f);
    float sd1 = sqrtf(fmaxf(q01.y * inv - me1 * me1, 0.0f) + 1e-5f);
    float sd2 = sqrtf(fmaxf(q23.x * inv - me2 * me2, 0.0f) + 1e-5f);
    float sd3 = sqrtf(fmaxf(q23.y * inv - me3 * me3, 0.0f) + 1e-5f);
    float fx0 = (float)mx01.x, fx1 = (float)mx01.y;
    float fx2 = (float)mx23.x, fx3 = (float)mx23.y;
    float fn0 = (float)mn01.x, fn1 = (float)mn01.y;
    float fn2 = (float)mn23.x, fn3 = (float)mn23.y;
    if (d == 0) {
        fx0 = fx1 = fx2 = fx3 = 0.0f;
        fn0 = fn1 = fn2 = fn3 = 0.0f;
    }
    u16* base = G + (size_t)n * D_G;
    #define PK2(a, b) ((u32)f2h(a) | ((u32)f2h(b) << 16))
    if (half == 0) {
        *(uint2*)(base + c4) = *(const uint2*)(h + (size_t)n * D_HIDC + c4);
        uint2 m; m.x = PK2(me0, me1); m.y = PK2(me2, me3);
        *(uint2*)(base + 128 + c4) = m;
        uint2 X; X.x = PK2(fx0, fx1); X.y = PK2(fx2, fx3);
        *(uint2*)(base + 256 + c4) = X;
    } else {
        uint2 N_; N_.x = PK2(fn0, fn1); N_.y = PK2(fn2, fn3);
        *(uint2*)(base + 384 + c4) = N_;
        uint2 S; S.x = PK2(sd0, sd1); S.y = PK2(sd2, sd3);
        *(uint2*)(base + 512 + c4) = S;
    }
    #undef PK2
}

// h_out[n][j] = relu(bias + G*W1 + am*(S*W2) + at*(S*W3))
// single pass over G: S-phase reads S once -> MFMA (W2, b*am_fp16) into acc,
// (W3, b) into ac3; G-phase (W1, b) into acc. Epilogue: acc + at*ac3 (f32).
// BK=64, XOR-swizzled LDS chunks -> conflict-free frags.
__global__ void __launch_bounds__(256) k_gemm(
        const u16* __restrict__ G, const u16* __restrict__ Wt,
        const int* __restrict__ deg, const float* __restrict__ delta_p,
        const float* __restrict__ bias, u16* __restrict__ hout) {
    __shared__ _Float16 A2[128 * 64];   // 16 KB (W2 in S-phase, W1 in G-phase)
    __shared__ _Float16 A3[128 * 64];   // 16 KB (W3)
    __shared__ _Float16 Bt[64 * 64];    // 8 KB
    const _Float16* Wf = (const _Float16*)Wt;
    const _Float16* Gf = (const _Float16*)G;
    int n0 = blockIdx.x * 64;
    int t = threadIdx.x;
    int w = t >> 6, lane = t & 63;
    int srow8 = lane >> 3, sslot = lane & 7;
    int stg = (sslot ^ srow8) * 8;        // swizzled source chunk offset
    int q4 = lane >> 4, r16 = lane & 15;
    int sx0 = (q4 ^ (lane & 7)) * 8;
    int sx1 = ((q4 + 4) ^ (lane & 7)) * 8;
    int col = lane & 15;

    float delta = delta_p[0];
    float atv[4];
    _Float16 amh[4];
    #pragma unroll
    for (int nt = 0; nt < 4; nt++) {
        int node = n0 + nt * 16 + col;
        float logd = logf((float)deg[node] + 1.0f);
        amh[nt] = (_Float16)(logd / delta);
        atv[nt] = delta / fmaxf(logd, 1e-5f);
    }

    f32x4 acc[2][4], ac3[2][4];
    #pragma unroll
    for (int a = 0; a < 2; a++)
        #pragma unroll
        for (int b = 0; b < 4; b++) {
            acc[a][b] = (f32x4){0.f, 0.f, 0.f, 0.f};
            ac3[a][b] = (f32x4){0.f, 0.f, 0.f, 0.f};
        }

    // ---- S-phase: B = G cols 128..639; A2 = W cols 640..1151; A3 = 1152..1663
    for (int ki = 0; ki < 8; ki++) {
        int k0 = ki * 64;
        __syncthreads();
        #pragma unroll
        for (int r = 0; r < 4; r++) {
            int arow = (r * 4 + w) * 8 + srow8;
            gll16(&A2[(r * 4 + w) * 512], Wf + (size_t)arow * D_WROW + 640 + k0 + stg);
            gll16(&A3[(r * 4 + w) * 512], Wf + (size_t)arow * D_WROW + 1152 + k0 + stg);
        }
        #pragma unroll
        for (int q = 0; q < 2; q++) {
            int brow = (q * 4 + w) * 8 + srow8;
            gll16(&Bt[(q * 4 + w) * 512], Gf + (size_t)(n0 + brow) * D_G + 128 + k0 + stg);
        }
        __syncthreads();
        f16x8 w2a0 = *(const f16x8*)&A2[(w * 32 + r16) * 64 + sx0];
        f16x8 w2a1 = *(const f16x8*)&A2[(w * 32 + r16) * 64 + sx1];
        f16x8 w2b0 = *(const f16x8*)&A2[(w * 32 + 16 + r16) * 64 + sx0];
        f16x8 w2b1 = *(const f16x8*)&A2[(w * 32 + 16 + r16) * 64 + sx1];
        f16x8 w3a0 = *(const f16x8*)&A3[(w * 32 + r16) * 64 + sx0];
        f16x8 w3a1 = *(const f16x8*)&A3[(w * 32 + r16) * 64 + sx1];
        f16x8 w3b0 = *(const f16x8*)&A3[(w * 32 + 16 + r16) * 64 + sx0];
        f16x8 w3b1 = *(const f16x8*)&A3[(w * 32 + 16 + r16) * 64 + sx1];
        #pragma unroll
        for (int nt = 0; nt < 4; nt++) {
            f16x8 b0 = *(const f16x8*)&Bt[(nt * 16 + r16) * 64 + sx0];
            f16x8 b1 = *(const f16x8*)&Bt[(nt * 16 + r16) * 64 + sx1];
            f16x8 bm0 = b0 * amh[nt];
            f16x8 bm1 = b1 * amh[nt];
            acc[0][nt] = __builtin_amdgcn_mfma_f32_16x16x32_f16(w2a0, bm0, acc[0][nt], 0, 0, 0);
            acc[1][nt] = __builtin_amdgcn_mfma_f32_16x16x32_f16(w2b0, bm0, acc[1][nt], 0, 0, 0);
            acc[0][nt] = __builtin_amdgcn_mfma_f32_16x16x32_f16(w2a1, bm1, acc[0][nt], 0, 0, 0);
            acc[1][nt] = __builtin_amdgcn_mfma_f32_16x16x32_f16(w2b1, bm1, acc[1][nt], 0, 0, 0);
            ac3[0][nt] = __builtin_amdgcn_mfma_f32_16x16x32_f16(w3a0, b0, ac3[0][nt], 0, 0, 0);
            ac3[1][nt] = __builtin_amdgcn_mfma_f32_16x16x32_f16(w3b0, b0, ac3[1][nt], 0, 0, 0);
            ac3[0][nt] = __builtin_amdgcn_mfma_f32_16x16x32_f16(w3a1, b1, ac3[0][nt], 0, 0, 0);
            ac3[1][nt] = __builtin_amdgcn_mfma_f32_16x16x32_f16(w3b1, b1, ac3[1][nt], 0, 0, 0);
        }
    }
    // ---- G-phase: B = G cols 0..639; A2 = W cols 0..639
    for (int ki = 0; ki < 10; ki++) {
        int k0 = ki * 64;
        __syncthreads();
        #pragma unroll
        for (int r = 0; r < 4; r++) {
            int arow = (r * 4 + w) * 8 + srow8;
            gll16(&A2[(r * 4 + w) * 512], Wf + (size_t)arow * D_WROW + k0 + stg);
        }
        #pragma unroll
        for (int q = 0; q < 2; q++) {
            int brow = (q * 4 + w) * 8 + srow8;
            gll16(&Bt[(q * 4 + w) * 512], Gf + (size_t)(n0 + brow) * D_G + k0 + stg);
        }
        __syncthreads();
        f16x8 a00 = *(const f16x8*)&A2[(w * 32 + r16) * 64 + sx0];
        f16x8 a01 = *(const f16x8*)&A2[(w * 32 + r16) * 64 + sx1];
        f16x8 a10 = *(const f16x8*)&A2[(w * 32 + 16 + r16) * 64 + sx0];
        f16x8 a11 = *(const f16x8*)&A2[(w * 32 + 16 + r16) * 64 + sx1];
        #pragma unroll
        for (int nt = 0; nt < 4; nt++) {
            f16x8 b0 = *(const f16x8*)&Bt[(nt * 16 + r16) * 64 + sx0];
            f16x8 b1 = *(const f16x8*)&Bt[(nt * 16 + r16) * 64 + sx1];
            acc[0][nt] = __builtin_amdgcn_mfma_f32_16x16x32_f16(a00, b0, acc[0][nt], 0, 0, 0);
            acc[1][nt] = __builtin_amdgcn_mfma_f32_16x16x32_f16(a10, b0, acc[1][nt], 0, 0, 0);
            acc[0][nt] = __builtin_amdgcn_mfma_f32_16x16x32_f16(a01, b1, acc[0][nt], 0, 0, 0);
            acc[1][nt] = __builtin_amdgcn_mfma_f32_16x16x32_f16(a11, b1, acc[1][nt], 0, 0, 0);
        }
    }
    // D[row=(lane>>4)*4+reg][col=lane&15]; row -> j, col -> node
    int rowq = q4 * 4;
    #pragma unroll
    for (int nt = 0; nt < 4; nt++) {
        int node = n0 + nt * 16 + col;
        float at = atv[nt];
        #pragma unroll
        for (int mt = 0; mt < 2; mt++) {
            int jb = w * 32 + mt * 16 + rowq;
            f32x4 v = acc[mt][nt], v3 = ac3[mt][nt];
            ushort4 o;
            o.x = f2h(fmaxf(v.x + at * v3.x + bias[jb], 0.0f));
            o.y = f2h(fmaxf(v.y + at * v3.y + bias[jb + 1], 0.0f));
            o.z = f2h(fmaxf(v.z + at * v3.z + bias[jb + 2], 0.0f));
            o.w = f2h(fmaxf(v.w + at * v3.w + bias[jb + 3], 0.0f));
            *(ushort4*)&hout[(size_t)node * D_HIDC + jb] = o;
        }
    }
}

// ---------------- epilogue kernels ----------------

__global__ void __launch_bounds__(256) k_pool(
        const u16* __restrict__ h, const int* __restrict__ goff,
        float* __restrict__ pooled) {
    __shared__ float sm[256];
    int g = blockIdx.x >> 2, s = blockIdx.x & 3;
    int gb = goff[g], ge = goff[g + 1];
    int len = ge - gb;
    int q = (len + 3) >> 2;
    int nb = gb + s * q;
    int ne = min(nb + q, ge);
    int t = threadIdx.x;
    int j = t & 127, half = t >> 7;
    float acc = 0.0f;
    for (int n = nb + half; n < ne; n += 2)
        acc += h2f(h[(size_t)n * D_HIDC + j]);
    sm[t] = acc; __syncthreads();
    if (t < 128) {
        float v = sm[t] + sm[t + 128];
        atomicAdd(&pooled[g * D_HIDC + j], v);
    }
}

// one block per graph; redundant mu/var recompute (pooled is tiny, L2-hot)
__global__ void __launch_bounds__(128) k_bn_fc(
        const float* __restrict__ pooled, const float* __restrict__ gamma,
        const float* __restrict__ beta, const float* __restrict__ fcW,
        const float* __restrict__ fcb, float* __restrict__ out) {
    __shared__ float bn[D_HIDC];
    int g = blockIdx.x, t = threadIdx.x;
    float s = 0.f, q = 0.f;
    for (int gg = 0; gg < N_GRAPHSC; gg++) {
        float v = pooled[gg * D_HIDC + t];
        s += v; q += v * v;
    }
    float mu = s * (1.0f / N_GRAPHSC);
    float var = q * (1.0f / N_GRAPHSC) - mu * mu;
    float inv = 1.0f / sqrtf(var + 1e-5f);
    bn[t] = (pooled[g * D_HIDC + t] - mu) * inv * gamma[t] + beta[t];
    __syncthreads();
    if (t < D_LATC) {
        float accum = fcb[t];
        for (int j = 0; j < D_HIDC; j++) accum += bn[j] * fcW[j * D_LATC + t];
        out[g * D_LATC + t] = accum;
    }
}

// ---------------- launch ----------------

extern "C" void kernel_launch(void* const* d_in, const int* in_sizes, int n_in,
                              void* d_out, int out_size, void* d_ws, size_t ws_size,
                              hipStream_t stream) {
    const float* x     = (const float*)d_in[0];
    const int*   ei    = (const int*)d_in[1];
    const int*   batch = (const int*)d_in[2];
    const float* W0 = (const float*)d_in[3];
    const float* b0 = (const float*)d_in[4];
    const float* W1 = (const float*)d_in[5];
    const float* b1 = (const float*)d_in[6];
    const float* W2 = (const float*)d_in[7];
    const float* b2 = (const float*)d_in[8];
    const float* gamma = (const float*)d_in[9];
    const float* beta  = (const float*)d_in[10];
    const float* fcW   = (const float*)d_in[11];
    const float* fcb   = (const float*)d_in[12];
    float* out = (float*)d_out;
    const int* srcv = ei;
    const int* dstv = ei + N_EDGESC;

    char* p = (char*)d_ws;
    auto alloc = [&](size_t bytes) -> char* {
        char* r = p;
        p += (bytes + 255) & ~(size_t)255;
        return r;
    };
    int*   deg_cnt = (int*)alloc((size_t)N_PAD * 4);
    int*   cursor  = (int*)alloc((size_t)N_NODESC * 4);
    float* delta_p = (float*)alloc(4);
    float* pooled  = (float*)alloc((size_t)N_GRAPHSC * D_HIDC * 4);
    char*  zero_end = p;
    int*   row_off = (int*)alloc((size_t)(N_NODESC + 1) * 4);
    int*   goff    = (int*)alloc((size_t)(N_GRAPHSC + 1) * 4);
    int*   csr_src = (int*)alloc((size_t)N_EDGESC * 4);
    u16*   Wt      = (u16*)alloc((size_t)3 * D_WROW * D_HIDC * 2);   // 1.28 MB
    u16*   hA      = (u16*)alloc((size_t)N_PAD * D_HIDC * 2);        // 12.8 MB
    u16*   hB      = (u16*)alloc((size_t)N_PAD * D_HIDC * 2);        // 12.8 MB
    u16*   G       = (u16*)alloc((size_t)N_PAD * D_G * 2);           // 64.1 MB

    int nz = (int)((zero_end - (char*)deg_cnt) / 4);
    int ZB = (nz + 255) / 256;
    int setup_grid = ZB + 12500 + 2496 + 1;
    k_setup<<<setup_grid, 256, 0, stream>>>(x, W0, W1, W2, batch,
                                            hB, Wt, deg_cnt, nz, ZB, goff);
    k_count<<<(N_EDGESC + 255) / 256, 256, 0, stream>>>(dstv, deg_cnt);
    k_scan_one<<<1, 1024, 0, stream>>>(deg_cnt, row_off, delta_p);
    k_fill_csr<<<(N_EDGESC + 255) / 256, 256, 0, stream>>>(srcv, dstv, row_off, cursor, csr_src);

    const float* bs[3] = {b0, b1, b2};
    const u16* h_in[3]  = {hB, hA, hB};
    u16*       h_out[3] = {hA, hB, hA};
    size_t wsz = (size_t)D_WROW * D_HIDC;
    for (int l = 0; l < 3; l++) {
        k_aggregate<<<(N_NODESC + 3) / 4, 256, 0, stream>>>(
            h_in[l], row_off, csr_src, G);
        k_gemm<<<N_PAD / 64, 256, 0, stream>>>(
            G, Wt + (size_t)l * wsz, deg_cnt, delta_p, bs[l], h_out[l]);
    }
    k_pool<<<4 * N_GRAPHSC, 256, 0, stream>>>(h_out[2], goff, pooled);
    k_bn_fc<<<N_GRAPHSC, 128, 0, stream>>>(pooled, gamma, beta, fcW, fcb, out);
}

// Round 9
// 450.827 us; speedup vs baseline: 1.1850x; 1.1850x over previous
//
#include <hip/hip_runtime.h>
#include <cstdint>
#include <cstddef>

#define N_NODESC 50000
#define N_PAD    50048   // 782 * 64
#define N_EDGESC 600000
#define N_GRAPHSC 64
#define D_HIDC   128
#define D_LATC   64
#define D_G      640     // h(128) + mean,mx,mn,std (4*128)
#define D_WROW   1664    // transposed W row length (13*128)

typedef unsigned short u16;
typedef unsigned int   u32;

typedef _Float16 f16x8 __attribute__((ext_vector_type(8)));
typedef _Float16 f16x2 __attribute__((ext_vector_type(2)));
typedef float    f32x4 __attribute__((ext_vector_type(4)));
typedef float    f32x2 __attribute__((ext_vector_type(2)));

__device__ __forceinline__ u16 f2h(float f) {
    return __builtin_bit_cast(u16, (_Float16)f);
}
__device__ __forceinline__ float h2f(u16 u) {
    return (float)__builtin_bit_cast(_Float16, u);
}

__device__ __forceinline__ void gll16(void* lds, const void* g) {
    // async global->LDS, 16B per lane; HW dest = wave-uniform base + lane*16
    __builtin_amdgcn_global_load_lds(
        (const __attribute__((address_space(1))) void*)g,
        (__attribute__((address_space(3))) void*)lds, 16, 0, 0);
}

// ---------------- fused setup ----------------
// block ranges: [0,ZB) zero | [ZB,ZB+12500) x2h | next 2496 wconv | last goff
__global__ void __launch_bounds__(256) k_setup(
        const float* __restrict__ x, const float* __restrict__ W0,
        const float* __restrict__ W1, const float* __restrict__ W2,
        const int* __restrict__ batch,
        u16* __restrict__ h, u16* __restrict__ Wt,
        int* __restrict__ zero_base, int nz, int ZB, int* __restrict__ goff) {
    int b = blockIdx.x;
    int t = threadIdx.x;
    if (b < ZB) {
        int i = b * 256 + t;
        if (i < nz) zero_base[i] = 0;
        return;
    }
    b -= ZB;
    if (b < 12500) {                       // x -> fp16 (2 elems/thread)
        int i = b * 256 + t;
        float2 v = ((const float2*)x)[i];
        ((u32*)h)[i] = (u32)f2h(v.x) | ((u32)f2h(v.y) << 16);
        return;
    }
    b -= 12500;
    if (b < 2496) {                        // W transpose+cast: [1664][128] -> [128][1664]
        int which = b / 832;
        int i = (b % 832) * 256 + t;
        const float* W = (which == 0) ? W0 : (which == 1) ? W1 : W2;
        int k = i / D_HIDC, j = i % D_HIDC;
        Wt[(size_t)which * D_WROW * D_HIDC + (size_t)j * D_WROW + k] = f2h(W[i]);
        return;
    }
    // goff via binary search over sorted batch
    int g = t;
    if (g <= N_GRAPHSC) {
        int lo = 0, hi = N_NODESC;
        while (lo < hi) {
            int mid = (lo + hi) >> 1;
            if (batch[mid] < g) lo = mid + 1; else hi = mid;
        }
        goff[g] = lo;
    }
}

__global__ void k_count(const int* __restrict__ dst, int* __restrict__ deg) {
    int e = blockIdx.x * 256 + threadIdx.x;
    if (e < N_EDGESC) atomicAdd(&deg[dst[e]], 1);
}

// 196 blocks: per-block int sum -> bsum, per-block logf sum -> lsum
__global__ void __launch_bounds__(256) k_scan_part(
        const int* __restrict__ deg, int* __restrict__ bsum,
        float* __restrict__ lsum) {
    __shared__ int s[256];
    __shared__ float ls[256];
    int idx = blockIdx.x * 256 + threadIdx.x;
    int v = (idx < N_NODESC) ? deg[idx] : 0;
    s[threadIdx.x] = v;
    ls[threadIdx.x] = (idx < N_NODESC) ? logf((float)v + 1.0f) : 0.0f;
    __syncthreads();
    for (int o = 128; o > 0; o >>= 1) {
        if (threadIdx.x < o) {
            s[threadIdx.x] += s[threadIdx.x + o];
            ls[threadIdx.x] += ls[threadIdx.x + o];
        }
        __syncthreads();
    }
    if (threadIdx.x == 0) { bsum[blockIdx.x] = s[0]; lsum[blockIdx.x] = ls[0]; }
}

// 1 block: exclusive-scan bsum (196 entries) + reduce lsum -> delta
__global__ void __launch_bounds__(256) k_scan_block(
        int* __restrict__ bsum, const float* __restrict__ lsum,
        float* __restrict__ delta_p) {
    __shared__ int s[256];
    __shared__ float ls[256];
    int t = threadIdx.x;
    int v = (t < 196) ? bsum[t] : 0;
    s[t] = v;
    ls[t] = (t < 196) ? lsum[t] : 0.0f;
    __syncthreads();
    for (int o = 1; o < 256; o <<= 1) {
        int add = (t >= o) ? s[t - o] : 0;
        __syncthreads();
        s[t] += add;
        __syncthreads();
    }
    if (t < 196) bsum[t] = s[t] - v;   // exclusive
    for (int o = 128; o > 0; o >>= 1) {
        if (t < o) ls[t] += ls[t + o];
        __syncthreads();
    }
    if (t == 0) delta_p[0] = ls[0] * (1.0f / (float)N_NODESC);
}

// 196 blocks: block-local exclusive scan + block offset -> row_off
__global__ void __launch_bounds__(256) k_scan_final(
        const int* __restrict__ deg, const int* __restrict__ bsum,
        int* __restrict__ row_off) {
    __shared__ int s[256];
    int t = threadIdx.x;
    int idx = blockIdx.x * 256 + t;
    int v = (idx < N_NODESC) ? deg[idx] : 0;
    s[t] = v; __syncthreads();
    for (int o = 1; o < 256; o <<= 1) {
        int add = (t >= o) ? s[t - o] : 0;
        __syncthreads();
        s[t] += add;
        __syncthreads();
    }
    int excl = s[t] - v + bsum[blockIdx.x];
    if (idx < N_NODESC) row_off[idx] = excl;
    if (idx == 0) row_off[N_NODESC] = N_EDGESC;
}

__global__ void k_fill_csr(const int* __restrict__ src, const int* __restrict__ dst,
                           const int* __restrict__ row_off, int* __restrict__ cursor,
                           int* __restrict__ csr_src) {
    int e = blockIdx.x * 256 + threadIdx.x;
    if (e < N_EDGESC) {
        int d = dst[e];
        int pos = row_off[d] + atomicAdd(&cursor[d], 1);
        csr_src[pos] = src[e];
    }
}

// ---------------- per-layer kernels ----------------

// one wave per node; two half-waves over alternate edges; packed fp16 min/max,
// packed f32 sum/sq. writes G[n] = [h, mean, max, min, std] fp16
__global__ void __launch_bounds__(256) k_aggregate(
        const u16* __restrict__ h, const int* __restrict__ row_off,
        const int* __restrict__ csr_src, u16* __restrict__ G) {
    int n = blockIdx.x * 4 + (threadIdx.x >> 6);
    if (n >= N_NODESC) return;
    int lane = threadIdx.x & 63;
    int half = lane >> 5, l32 = lane & 31;
    int c4 = 4 * l32;
    int beg = row_off[n], end = row_off[n + 1];
    f32x2 s01 = {0.f, 0.f}, s23 = {0.f, 0.f};
    f32x2 q01 = {0.f, 0.f}, q23 = {0.f, 0.f};
    const _Float16 NEG = (_Float16)(-65504.0f), POS = (_Float16)(65504.0f);
    f16x2 mx01 = {NEG, NEG}, mx23 = {NEG, NEG};
    f16x2 mn01 = {POS, POS}, mn23 = {POS, POS};

    #define PROC(u) { \
        f16x2 p01 = __builtin_bit_cast(f16x2, (u).x); \
        f16x2 p23 = __builtin_bit_cast(f16x2, (u).y); \
        f32x2 c01 = __builtin_convertvector(p01, f32x2); \
        f32x2 c23 = __builtin_convertvector(p23, f32x2); \
        s01 += c01; s23 += c23; \
        q01 += c01 * c01; q23 += c23 * c23; \
        mx01 = __builtin_elementwise_max(mx01, p01); \
        mx23 = __builtin_elementwise_max(mx23, p23); \
        mn01 = __builtin_elementwise_min(mn01, p01); \
        mn23 = __builtin_elementwise_min(mn23, p23); }

    int i = beg + half;
    for (; i + 2 < end; i += 4) {
        int ea = csr_src[i], eb = csr_src[i + 2];
        uint2 ua = *(const uint2*)(h + (size_t)ea * D_HIDC + c4);
        uint2 ub = *(const uint2*)(h + (size_t)eb * D_HIDC + c4);
        PROC(ua);
        PROC(ub);
    }
    if (i < end) {
        int ea = csr_src[i];
        uint2 ua = *(const uint2*)(h + (size_t)ea * D_HIDC + c4);
        PROC(ua);
    }
    #undef PROC

    // merge half-waves
    s01.x += __shfl_xor(s01.x, 32); s01.y += __shfl_xor(s01.y, 32);
    s23.x += __shfl_xor(s23.x, 32); s23.y += __shfl_xor(s23.y, 32);
    q01.x += __shfl_xor(q01.x, 32); q01.y += __shfl_xor(q01.y, 32);
    q23.x += __shfl_xor(q23.x, 32); q23.y += __shfl_xor(q23.y, 32);
    mx01 = __builtin_elementwise_max(mx01,
        __builtin_bit_cast(f16x2, __shfl_xor(__builtin_bit_cast(int, mx01), 32)));
    mx23 = __builtin_elementwise_max(mx23,
        __builtin_bit_cast(f16x2, __shfl_xor(__builtin_bit_cast(int, mx23), 32)));
    mn01 = __builtin_elementwise_min(mn01,
        __builtin_bit_cast(f16x2, __shfl_xor(__builtin_bit_cast(int, mn01), 32)));
    mn23 = __builtin_elementwise_min(mn23,
        __builtin_bit_cast(f16x2, __shfl_xor(__builtin_bit_cast(int, mn23), 32)));

    int d = end - beg;
    float inv = 1.0f / fmaxf((float)d, 1.0f);
    float me0 = s01.x * inv, me1 = s01.y * inv, me2 = s23.x * inv, me3 = s23.y * inv;
    float sd0 = sqrtf(fmaxf(q01.x * inv - me0 * me0, 0.0f) + 1e-5f);
    float sd1 = sqrtf(fmaxf(q01.y * inv - me1 * me1, 0.0f) + 1e-5f);
    float sd2 = sqrtf(fmaxf(q23.x * inv - me2 * me2, 0.0f) + 1e-5f);
    float sd3 = sqrtf(fmaxf(q23.y * inv - me3 * me3, 0.0f) + 1e-5f);
    float fx0 = (float)mx01.x, fx1 = (float)mx01.y;
    float fx2 = (float)mx23.x, fx3 = (float)mx23.y;
    float fn0 = (float)mn01.x, fn1 = (float)mn01.y;
    float fn2 = (float)mn23.x, fn3 = (float)mn23.y;
    if (d == 0) {
        fx0 = fx1 = fx2 = fx3 = 0.0f;
        fn0 = fn1 = fn2 = fn3 = 0.0f;
    }
    u16* base = G + (size_t)n * D_G;
    #define PK2(a, b) ((u32)f2h(a) | ((u32)f2h(b) << 16))
    if (half == 0) {
        *(uint2*)(base + c4) = *(const uint2*)(h + (size_t)n * D_HIDC + c4);
        uint2 m; m.x = PK2(me0, me1); m.y = PK2(me2, me3);
        *(uint2*)(base + 128 + c4) = m;
        uint2 X; X.x = PK2(fx0, fx1); X.y = PK2(fx2, fx3);
        *(uint2*)(base + 256 + c4) = X;
    } else {
        uint2 N_; N_.x = PK2(fn0, fn1); N_.y = PK2(fn2, fn3);
        *(uint2*)(base + 384 + c4) = N_;
        uint2 S; S.x = PK2(sd0, sd1); S.y = PK2(sd2, sd3);
        *(uint2*)(base + 512 + c4) = S;
    }
    #undef PK2
}

// h_out[n][j] = relu(bias + G*W1 + am*(S*W2) + at*(S*W3))
// single pass over G: S-phase reads S once -> MFMA (W2, b*am_fp16) into acc,
// (W3, b) into ac3; G-phase (W1, b) into acc. Epilogue: acc + at*ac3 (f32).
// BK=64, XOR-swizzled LDS chunks -> conflict-free frags.
__global__ void __launch_bounds__(256) k_gemm(
        const u16* __restrict__ G, const u16* __restrict__ Wt,
        const int* __restrict__ deg, const float* __restrict__ delta_p,
        const float* __restrict__ bias, u16* __restrict__ hout) {
    __shared__ _Float16 A2[128 * 64];   // 16 KB (W2 in S-phase, W1 in G-phase)
    __shared__ _Float16 A3[128 * 64];   // 16 KB (W3)
    __shared__ _Float16 Bt[64 * 64];    // 8 KB
    const _Float16* Wf = (const _Float16*)Wt;
    const _Float16* Gf = (const _Float16*)G;
    int n0 = blockIdx.x * 64;
    int t = threadIdx.x;
    int w = t >> 6, lane = t & 63;
    int srow8 = lane >> 3, sslot = lane & 7;
    int stg = (sslot ^ srow8) * 8;        // swizzled source chunk offset
    int q4 = lane >> 4, r16 = lane & 15;
    int sx0 = (q4 ^ (lane & 7)) * 8;
    int sx1 = ((q4 + 4) ^ (lane & 7)) * 8;
    int col = lane & 15;

    float delta = delta_p[0];
    float atv[4];
    _Float16 amh[4];
    #pragma unroll
    for (int nt = 0; nt < 4; nt++) {
        int node = n0 + nt * 16 + col;
        float logd = logf((float)deg[node] + 1.0f);
        amh[nt] = (_Float16)(logd / delta);
        atv[nt] = delta / fmaxf(logd, 1e-5f);
    }

    f32x4 acc[2][4], ac3[2][4];
    #pragma unroll
    for (int a = 0; a < 2; a++)
        #pragma unroll
        for (int b = 0; b < 4; b++) {
            acc[a][b] = (f32x4){0.f, 0.f, 0.f, 0.f};
            ac3[a][b] = (f32x4){0.f, 0.f, 0.f, 0.f};
        }

    // ---- S-phase: B = G cols 128..639; A2 = W cols 640..1151; A3 = 1152..1663
    for (int ki = 0; ki < 8; ki++) {
        int k0 = ki * 64;
        __syncthreads();
        #pragma unroll
        for (int r = 0; r < 4; r++) {
            int arow = (r * 4 + w) * 8 + srow8;
            gll16(&A2[(r * 4 + w) * 512], Wf + (size_t)arow * D_WROW + 640 + k0 + stg);
            gll16(&A3[(r * 4 + w) * 512], Wf + (size_t)arow * D_WROW + 1152 + k0 + stg);
        }
        #pragma unroll
        for (int q = 0; q < 2; q++) {
            int brow = (q * 4 + w) * 8 + srow8;
            gll16(&Bt[(q * 4 + w) * 512], Gf + (size_t)(n0 + brow) * D_G + 128 + k0 + stg);
        }
        __syncthreads();
        f16x8 w2a0 = *(const f16x8*)&A2[(w * 32 + r16) * 64 + sx0];
        f16x8 w2a1 = *(const f16x8*)&A2[(w * 32 + r16) * 64 + sx1];
        f16x8 w2b0 = *(const f16x8*)&A2[(w * 32 + 16 + r16) * 64 + sx0];
        f16x8 w2b1 = *(const f16x8*)&A2[(w * 32 + 16 + r16) * 64 + sx1];
        f16x8 w3a0 = *(const f16x8*)&A3[(w * 32 + r16) * 64 + sx0];
        f16x8 w3a1 = *(const f16x8*)&A3[(w * 32 + r16) * 64 + sx1];
        f16x8 w3b0 = *(const f16x8*)&A3[(w * 32 + 16 + r16) * 64 + sx0];
        f16x8 w3b1 = *(const f16x8*)&A3[(w * 32 + 16 + r16) * 64 + sx1];
        #pragma unroll
        for (int nt = 0; nt < 4; nt++) {
            f16x8 b0 = *(const f16x8*)&Bt[(nt * 16 + r16) * 64 + sx0];
            f16x8 b1 = *(const f16x8*)&Bt[(nt * 16 + r16) * 64 + sx1];
            f16x8 bm0 = b0 * amh[nt];
            f16x8 bm1 = b1 * amh[nt];
            acc[0][nt] = __builtin_amdgcn_mfma_f32_16x16x32_f16(w2a0, bm0, acc[0][nt], 0, 0, 0);
            acc[1][nt] = __builtin_amdgcn_mfma_f32_16x16x32_f16(w2b0, bm0, acc[1][nt], 0, 0, 0);
            acc[0][nt] = __builtin_amdgcn_mfma_f32_16x16x32_f16(w2a1, bm1, acc[0][nt], 0, 0, 0);
            acc[1][nt] = __builtin_amdgcn_mfma_f32_16x16x32_f16(w2b1, bm1, acc[1][nt], 0, 0, 0);
            ac3[0][nt] = __builtin_amdgcn_mfma_f32_16x16x32_f16(w3a0, b0, ac3[0][nt], 0, 0, 0);
            ac3[1][nt] = __builtin_amdgcn_mfma_f32_16x16x32_f16(w3b0, b0, ac3[1][nt], 0, 0, 0);
            ac3[0][nt] = __builtin_amdgcn_mfma_f32_16x16x32_f16(w3a1, b1, ac3[0][nt], 0, 0, 0);
            ac3[1][nt] = __builtin_amdgcn_mfma_f32_16x16x32_f16(w3b1, b1, ac3[1][nt], 0, 0, 0);
        }
    }
    // ---- G-phase: B = G cols 0..639; A2 = W cols 0..639
    for (int ki = 0; ki < 10; ki++) {
        int k0 = ki * 64;
        __syncthreads();
        #pragma unroll
        for (int r = 0; r < 4; r++) {
            int arow = (r * 4 + w) * 8 + srow8;
            gll16(&A2[(r * 4 + w) * 512], Wf + (size_t)arow * D_WROW + k0 + stg);
        }
        #pragma unroll
        for (int q = 0; q < 2; q++) {
            int brow = (q * 4 + w) * 8 + srow8;
            gll16(&Bt[(q * 4 + w) * 512], Gf + (size_t)(n0 + brow) * D_G + k0 + stg);
        }
        __syncthreads();
        f16x8 a00 = *(const f16x8*)&A2[(w * 32 + r16) * 64 + sx0];
        f16x8 a01 = *(const f16x8*)&A2[(w * 32 + r16) * 64 + sx1];
        f16x8 a10 = *(const f16x8*)&A2[(w * 32 + 16 + r16) * 64 + sx0];
        f16x8 a11 = *(const f16x8*)&A2[(w * 32 + 16 + r16) * 64 + sx1];
        #pragma unroll
        for (int nt = 0; nt < 4; nt++) {
            f16x8 b0 = *(const f16x8*)&Bt[(nt * 16 + r16) * 64 + sx0];
            f16x8 b1 = *(const f16x8*)&Bt[(nt * 16 + r16) * 64 + sx1];
            acc[0][nt] = __builtin_amdgcn_mfma_f32_16x16x32_f16(a00, b0, acc[0][nt], 0, 0, 0);
            acc[1][nt] = __builtin_amdgcn_mfma_f32_16x16x32_f16(a10, b0, acc[1][nt], 0, 0, 0);
            acc[0][nt] = __builtin_amdgcn_mfma_f32_16x16x32_f16(a01, b1, acc[0][nt], 0, 0, 0);
            acc[1][nt] = __builtin_amdgcn_mfma_f32_16x16x32_f16(a11, b1, acc[1][nt], 0, 0, 0);
        }
    }
    // D[row=(lane>>4)*4+reg][col=lane&15]; row -> j, col -> node
    int rowq = q4 * 4;
    #pragma unroll
    for (int nt = 0; nt < 4; nt++) {
        int node = n0 + nt * 16 + col;
        float at = atv[nt];
        #pragma unroll
        for (int mt = 0; mt < 2; mt++) {
            int jb = w * 32 + mt * 16 + rowq;
            f32x4 v = acc[mt][nt], v3 = ac3[mt][nt];
            ushort4 o;
            o.x = f2h(fmaxf(v.x + at * v3.x + bias[jb], 0.0f));
            o.y = f2h(fmaxf(v.y + at * v3.y + bias[jb + 1], 0.0f));
            o.z = f2h(fmaxf(v.z + at * v3.z + bias[jb + 2], 0.0f));
            o.w = f2h(fmaxf(v.w + at * v3.w + bias[jb + 3], 0.0f));
            *(ushort4*)&hout[(size_t)node * D_HIDC + jb] = o;
        }
    }
}

// ---------------- epilogue kernels ----------------

__global__ void __launch_bounds__(256) k_pool(
        const u16* __restrict__ h, const int* __restrict__ goff,
        float* __restrict__ pooled) {
    __shared__ float sm[256];
    int g = blockIdx.x >> 2, s = blockIdx.x & 3;
    int gb = goff[g], ge = goff[g + 1];
    int len = ge - gb;
    int q = (len + 3) >> 2;
    int nb = gb + s * q;
    int ne = min(nb + q, ge);
    int t = threadIdx.x;
    int j = t & 127, half = t >> 7;
    float acc = 0.0f;
    for (int n = nb + half; n < ne; n += 2)
        acc += h2f(h[(size_t)n * D_HIDC + j]);
    sm[t] = acc; __syncthreads();
    if (t < 128) {
        float v = sm[t] + sm[t + 128];
        atomicAdd(&pooled[g * D_HIDC + j], v);
    }
}

// one block per graph; redundant mu/var recompute (pooled is tiny, L2-hot)
__global__ void __launch_bounds__(128) k_bn_fc(
        const float* __restrict__ pooled, const float* __restrict__ gamma,
        const float* __restrict__ beta, const float* __restrict__ fcW,
        const float* __restrict__ fcb, float* __restrict__ out) {
    __shared__ float bn[D_HIDC];
    int g = blockIdx.x, t = threadIdx.x;
    float s = 0.f, q = 0.f;
    for (int gg = 0; gg < N_GRAPHSC; gg++) {
        float v = pooled[gg * D_HIDC + t];
        s += v; q += v * v;
    }
    float mu = s * (1.0f / N_GRAPHSC);
    float var = q * (1.0f / N_GRAPHSC) - mu * mu;
    float inv = 1.0f / sqrtf(var + 1e-5f);
    bn[t] = (pooled[g * D_HIDC + t] - mu) * inv * gamma[t] + beta[t];
    __syncthreads();
    if (t < D_LATC) {
        float accum = fcb[t];
        for (int j = 0; j < D_HIDC; j++) accum += bn[j] * fcW[j * D_LATC + t];
        out[g * D_LATC + t] = accum;
    }
}

// ---------------- launch ----------------

extern "C" void kernel_launch(void* const* d_in, const int* in_sizes, int n_in,
                              void* d_out, int out_size, void* d_ws, size_t ws_size,
                              hipStream_t stream) {
    const float* x     = (const float*)d_in[0];
    const int*   ei    = (const int*)d_in[1];
    const int*   batch = (const int*)d_in[2];
    const float* W0 = (const float*)d_in[3];
    const float* b0 = (const float*)d_in[4];
    const float* W1 = (const float*)d_in[5];
    const float* b1 = (const float*)d_in[6];
    const float* W2 = (const float*)d_in[7];
    const float* b2 = (const float*)d_in[8];
    const float* gamma = (const float*)d_in[9];
    const float* beta  = (const float*)d_in[10];
    const float* fcW   = (const float*)d_in[11];
    const float* fcb   = (const float*)d_in[12];
    float* out = (float*)d_out;
    const int* srcv = ei;
    const int* dstv = ei + N_EDGESC;

    char* p = (char*)d_ws;
    auto alloc = [&](size_t bytes) -> char* {
        char* r = p;
        p += (bytes + 255) & ~(size_t)255;
        return r;
    };
    int*   deg_cnt = (int*)alloc((size_t)N_PAD * 4);
    int*   cursor  = (int*)alloc((size_t)N_NODESC * 4);
    float* delta_p = (float*)alloc(4);
    float* pooled  = (float*)alloc((size_t)N_GRAPHSC * D_HIDC * 4);
    char*  zero_end = p;
    int*   row_off = (int*)alloc((size_t)(N_NODESC + 1) * 4);
    int*   goff    = (int*)alloc((size_t)(N_GRAPHSC + 1) * 4);
    int*   bsum    = (int*)alloc(256 * 4);
    float* lsum    = (float*)alloc(256 * 4);
    int*   csr_src = (int*)alloc((size_t)N_EDGESC * 4);
    u16*   Wt      = (u16*)alloc((size_t)3 * D_WROW * D_HIDC * 2);   // 1.28 MB
    u16*   hA      = (u16*)alloc((size_t)N_PAD * D_HIDC * 2);        // 12.8 MB
    u16*   hB      = (u16*)alloc((size_t)N_PAD * D_HIDC * 2);        // 12.8 MB
    u16*   G       = (u16*)alloc((size_t)N_PAD * D_G * 2);           // 64.1 MB

    int nz = (int)((zero_end - (char*)deg_cnt) / 4);
    int ZB = (nz + 255) / 256;
    int setup_grid = ZB + 12500 + 2496 + 1;
    k_setup<<<setup_grid, 256, 0, stream>>>(x, W0, W1, W2, batch,
                                            hB, Wt, deg_cnt, nz, ZB, goff);
    k_count<<<(N_EDGESC + 255) / 256, 256, 0, stream>>>(dstv, deg_cnt);
    k_scan_part<<<196, 256, 0, stream>>>(deg_cnt, bsum, lsum);
    k_scan_block<<<1, 256, 0, stream>>>(bsum, lsum, delta_p);
    k_scan_final<<<196, 256, 0, stream>>>(deg_cnt, bsum, row_off);
    k_fill_csr<<<(N_EDGESC + 255) / 256, 256, 0, stream>>>(srcv, dstv, row_off, cursor, csr_src);

    const float* bs[3] = {b0, b1, b2};
    const u16* h_in[3]  = {hB, hA, hB};
    u16*       h_out[3] = {hA, hB, hA};
    size_t wsz = (size_t)D_WROW * D_HIDC;
    for (int l = 0; l < 3; l++) {
        k_aggregate<<<(N_NODESC + 3) / 4, 256, 0, stream>>>(
            h_in[l], row_off, csr_src, G);
        k_gemm<<<N_PAD / 64, 256, 0, stream>>>(
            G, Wt + (size_t)l * wsz, deg_cnt, delta_p, bs[l], h_out[l]);
    }
    k_pool<<<4 * N_GRAPHSC, 256, 0, stream>>>(h_out[2], goff, pooled);
    k_bn_fc<<<N_GRAPHSC, 128, 0, stream>>>(pooled, gamma, beta, fcW, fcb, out);
}

// Round 11
// 422.486 us; speedup vs baseline: 1.2645x; 1.0671x over previous
//
#include <hip/hip_runtime.h>
#include <cstdint>
#include <cstddef>

#define N_NODESC 50000
#define N_PAD    50048   // 782 * 64
#define N_EDGESC 600000
#define N_GRAPHSC 64
#define D_HIDC   128
#define D_LATC   64
#define D_G      640     // h(128) + mean,mx,mn,std (4*128)
#define D_WROW   1664    // transposed W row length (13*128)

typedef unsigned short u16;
typedef unsigned int   u32;

typedef _Float16 f16x8 __attribute__((ext_vector_type(8)));
typedef _Float16 f16x2 __attribute__((ext_vector_type(2)));
typedef float    f32x4 __attribute__((ext_vector_type(4)));
typedef float    f32x2 __attribute__((ext_vector_type(2)));

__device__ __forceinline__ u16 f2h(float f) {
    return __builtin_bit_cast(u16, (_Float16)f);
}
__device__ __forceinline__ float h2f(u16 u) {
    return (float)__builtin_bit_cast(_Float16, u);
}

__device__ __forceinline__ void gll16(void* lds, const void* g) {
    // async global->LDS, 16B per lane; HW dest = wave-uniform base + lane*16
    __builtin_amdgcn_global_load_lds(
        (const __attribute__((address_space(1))) void*)g,
        (__attribute__((address_space(3))) void*)lds, 16, 0, 0);
}

// ---------------- fused setup ----------------
// block ranges: [0,ZB) zero | [ZB,ZB+12500) x2h | next 2496 wconv | last goff
__global__ void __launch_bounds__(256) k_setup(
        const float* __restrict__ x, const float* __restrict__ W0,
        const float* __restrict__ W1, const float* __restrict__ W2,
        const int* __restrict__ batch,
        u16* __restrict__ h, u16* __restrict__ Wt,
        int* __restrict__ zero_base, int nz, int ZB, int* __restrict__ goff) {
    int b = blockIdx.x;
    int t = threadIdx.x;
    if (b < ZB) {
        int i = b * 256 + t;
        if (i < nz) zero_base[i] = 0;
        return;
    }
    b -= ZB;
    if (b < 12500) {                       // x -> fp16 (2 elems/thread)
        int i = b * 256 + t;
        float2 v = ((const float2*)x)[i];
        ((u32*)h)[i] = (u32)f2h(v.x) | ((u32)f2h(v.y) << 16);
        return;
    }
    b -= 12500;
    if (b < 2496) {                        // W transpose+cast: [1664][128] -> [128][1664]
        int which = b / 832;
        int i = (b % 832) * 256 + t;
        const float* W = (which == 0) ? W0 : (which == 1) ? W1 : W2;
        int k = i / D_HIDC, j = i % D_HIDC;
        Wt[(size_t)which * D_WROW * D_HIDC + (size_t)j * D_WROW + k] = f2h(W[i]);
        return;
    }
    // goff via binary search over sorted batch
    int g = t;
    if (g <= N_GRAPHSC) {
        int lo = 0, hi = N_NODESC;
        while (lo < hi) {
            int mid = (lo + hi) >> 1;
            if (batch[mid] < g) lo = mid + 1; else hi = mid;
        }
        goff[g] = lo;
    }
}

__global__ void k_count(const int* __restrict__ dst, int* __restrict__ deg) {
    int e = blockIdx.x * 256 + threadIdx.x;
    if (e < N_EDGESC) atomicAdd(&deg[dst[e]], 1);
}

// 196 blocks: per-block int sum -> bsum, per-block logf sum -> lsum
__global__ void __launch_bounds__(256) k_scan_part(
        const int* __restrict__ deg, int* __restrict__ bsum,
        float* __restrict__ lsum) {
    __shared__ int s[256];
    __shared__ float ls[256];
    int idx = blockIdx.x * 256 + threadIdx.x;
    int v = (idx < N_NODESC) ? deg[idx] : 0;
    s[threadIdx.x] = v;
    ls[threadIdx.x] = (idx < N_NODESC) ? logf((float)v + 1.0f) : 0.0f;
    __syncthreads();
    for (int o = 128; o > 0; o >>= 1) {
        if (threadIdx.x < o) {
            s[threadIdx.x] += s[threadIdx.x + o];
            ls[threadIdx.x] += ls[threadIdx.x + o];
        }
        __syncthreads();
    }
    if (threadIdx.x == 0) { bsum[blockIdx.x] = s[0]; lsum[blockIdx.x] = ls[0]; }
}

// 1 block: exclusive-scan bsum (196 entries) + reduce lsum -> delta
__global__ void __launch_bounds__(256) k_scan_block(
        int* __restrict__ bsum, const float* __restrict__ lsum,
        float* __restrict__ delta_p) {
    __shared__ int s[256];
    __shared__ float ls[256];
    int t = threadIdx.x;
    int v = (t < 196) ? bsum[t] : 0;
    s[t] = v;
    ls[t] = (t < 196) ? lsum[t] : 0.0f;
    __syncthreads();
    for (int o = 1; o < 256; o <<= 1) {
        int add = (t >= o) ? s[t - o] : 0;
        __syncthreads();
        s[t] += add;
        __syncthreads();
    }
    if (t < 196) bsum[t] = s[t] - v;   // exclusive
    for (int o = 128; o > 0; o >>= 1) {
        if (t < o) ls[t] += ls[t + o];
        __syncthreads();
    }
    if (t == 0) delta_p[0] = ls[0] * (1.0f / (float)N_NODESC);
}

// 196 blocks: block-local exclusive scan + block offset -> row_off
__global__ void __launch_bounds__(256) k_scan_final(
        const int* __restrict__ deg, const int* __restrict__ bsum,
        int* __restrict__ row_off) {
    __shared__ int s[256];
    int t = threadIdx.x;
    int idx = blockIdx.x * 256 + t;
    int v = (idx < N_NODESC) ? deg[idx] : 0;
    s[t] = v; __syncthreads();
    for (int o = 1; o < 256; o <<= 1) {
        int add = (t >= o) ? s[t - o] : 0;
        __syncthreads();
        s[t] += add;
        __syncthreads();
    }
    int excl = s[t] - v + bsum[blockIdx.x];
    if (idx < N_NODESC) row_off[idx] = excl;
    if (idx == 0) row_off[N_NODESC] = N_EDGESC;
}

__global__ void k_fill_csr(const int* __restrict__ src, const int* __restrict__ dst,
                           const int* __restrict__ row_off, int* __restrict__ cursor,
                           int* __restrict__ csr_src) {
    int e = blockIdx.x * 256 + threadIdx.x;
    if (e < N_EDGESC) {
        int d = dst[e];
        int pos = row_off[d] + atomicAdd(&cursor[d], 1);
        csr_src[pos] = src[e];
    }
}

// ---------------- per-layer kernels ----------------

// one wave per node; two half-waves over alternate edges; 4 loads in flight
// per half-wave; f32 packed sum/sq (order-robust), exact fp16 packed min/max.
// writes G[n] = [h, mean, max, min, std] fp16
__global__ void __launch_bounds__(256) k_aggregate(
        const u16* __restrict__ h, const int* __restrict__ row_off,
        const int* __restrict__ csr_src, u16* __restrict__ G) {
    int n = blockIdx.x * 4 + (threadIdx.x >> 6);
    if (n >= N_NODESC) return;
    int lane = threadIdx.x & 63;
    int half = lane >> 5, l32 = lane & 31;
    int c4 = 4 * l32;
    int beg = row_off[n], end = row_off[n + 1];
    const _Float16 NEG = (_Float16)(-65504.0f), POS = (_Float16)(65504.0f);
    f32x2 s01 = {0.f, 0.f}, s23 = {0.f, 0.f};
    f32x2 q01 = {0.f, 0.f}, q23 = {0.f, 0.f};
    f16x2 mx01 = {NEG, NEG}, mx23 = {NEG, NEG};
    f16x2 mn01 = {POS, POS}, mn23 = {POS, POS};

    #define PROC(u) { \
        f16x2 p01 = __builtin_bit_cast(f16x2, (u).x); \
        f16x2 p23 = __builtin_bit_cast(f16x2, (u).y); \
        f32x2 c01 = __builtin_convertvector(p01, f32x2); \
        f32x2 c23 = __builtin_convertvector(p23, f32x2); \
        s01 += c01; s23 += c23; \
        q01 += c01 * c01; q23 += c23 * c23; \
        mx01 = __builtin_elementwise_max(mx01, p01); \
        mx23 = __builtin_elementwise_max(mx23, p23); \
        mn01 = __builtin_elementwise_min(mn01, p01); \
        mn23 = __builtin_elementwise_min(mn23, p23); }

    int i = beg + half;
    for (; i + 6 < end; i += 8) {
        int e0 = csr_src[i],     e1 = csr_src[i + 2];
        int e2 = csr_src[i + 4], e3 = csr_src[i + 6];
        uint2 u0 = *(const uint2*)(h + (size_t)e0 * D_HIDC + c4);
        uint2 u1 = *(const uint2*)(h + (size_t)e1 * D_HIDC + c4);
        uint2 u2 = *(const uint2*)(h + (size_t)e2 * D_HIDC + c4);
        uint2 u3 = *(const uint2*)(h + (size_t)e3 * D_HIDC + c4);
        PROC(u0); PROC(u1); PROC(u2); PROC(u3);
    }
    for (; i < end; i += 2) {
        int e0 = csr_src[i];
        uint2 u0 = *(const uint2*)(h + (size_t)e0 * D_HIDC + c4);
        PROC(u0);
    }
    #undef PROC

    // merge half-waves (lane^32 holds same columns, other edges)
    s01.x += __shfl_xor(s01.x, 32); s01.y += __shfl_xor(s01.y, 32);
    s23.x += __shfl_xor(s23.x, 32); s23.y += __shfl_xor(s23.y, 32);
    q01.x += __shfl_xor(q01.x, 32); q01.y += __shfl_xor(q01.y, 32);
    q23.x += __shfl_xor(q23.x, 32); q23.y += __shfl_xor(q23.y, 32);
    #define MRG(v, OP) v = OP(v, \
        __builtin_bit_cast(f16x2, __shfl_xor(__builtin_bit_cast(int, v), 32)))
    MRG(mx01, __builtin_elementwise_max); MRG(mx23, __builtin_elementwise_max);
    MRG(mn01, __builtin_elementwise_min); MRG(mn23, __builtin_elementwise_min);
    #undef MRG

    int d = end - beg;
    float inv = 1.0f / fmaxf((float)d, 1.0f);
    float me0 = s01.x * inv, me1 = s01.y * inv;
    float me2 = s23.x * inv, me3 = s23.y * inv;
    float sd0 = sqrtf(fmaxf(q01.x * inv - me0 * me0, 0.0f) + 1e-5f);
    float sd1 = sqrtf(fmaxf(q01.y * inv - me1 * me1, 0.0f) + 1e-5f);
    float sd2 = sqrtf(fmaxf(q23.x * inv - me2 * me2, 0.0f) + 1e-5f);
    float sd3 = sqrtf(fmaxf(q23.y * inv - me3 * me3, 0.0f) + 1e-5f);
    float fx0 = (float)mx01.x, fx1 = (float)mx01.y;
    float fx2 = (float)mx23.x, fx3 = (float)mx23.y;
    float fn0 = (float)mn01.x, fn1 = (float)mn01.y;
    float fn2 = (float)mn23.x, fn3 = (float)mn23.y;
    if (d == 0) {
        fx0 = fx1 = fx2 = fx3 = 0.0f;
        fn0 = fn1 = fn2 = fn3 = 0.0f;
    }
    u16* base = G + (size_t)n * D_G;
    #define PK2(a, b) ((u32)f2h(a) | ((u32)f2h(b) << 16))
    if (half == 0) {
        *(uint2*)(base + c4) = *(const uint2*)(h + (size_t)n * D_HIDC + c4);
        uint2 m; m.x = PK2(me0, me1); m.y = PK2(me2, me3);
        *(uint2*)(base + 128 + c4) = m;
        uint2 X; X.x = PK2(fx0, fx1); X.y = PK2(fx2, fx3);
        *(uint2*)(base + 256 + c4) = X;
    } else {
        uint2 N_; N_.x = PK2(fn0, fn1); N_.y = PK2(fn2, fn3);
        *(uint2*)(base + 384 + c4) = N_;
        uint2 S; S.x = PK2(sd0, sd1); S.y = PK2(sd2, sd3);
        *(uint2*)(base + 512 + c4) = S;
    }
    #undef PK2
}

// h_out[n][j] = relu(bias + G*W1 + am*(S*W2) + at*(S*W3))
// SINGLE loop over G cols 0..639 (BK=64, 10 iters). For k0>=128 the B-tile is
// in the S-range: also stage W2 (Wt col 512+k0) and W3 (1024+k0) and issue
// W2*(b*am_fp16) -> acc and W3*b -> ac3 against the same B. Epilogue: acc+at*ac3.
// XOR-swizzled LDS chunks -> conflict-free frags.
__global__ void __launch_bounds__(256) k_gemm(
        const u16* __restrict__ G, const u16* __restrict__ Wt,
        const int* __restrict__ deg, const float* __restrict__ delta_p,
        const float* __restrict__ bias, u16* __restrict__ hout) {
    __shared__ _Float16 A1[128 * 64];   // 16 KB (W1)
    __shared__ _Float16 A2[128 * 64];   // 16 KB (W2)
    __shared__ _Float16 A3[128 * 64];   // 16 KB (W3)
    __shared__ _Float16 Bt[64 * 64];    // 8 KB
    const _Float16* Wf = (const _Float16*)Wt;
    const _Float16* Gf = (const _Float16*)G;
    int n0 = blockIdx.x * 64;
    int t = threadIdx.x;
    int w = t >> 6, lane = t & 63;
    int srow8 = lane >> 3, sslot = lane & 7;
    int stg = (sslot ^ srow8) * 8;        // swizzled source chunk offset
    int q4 = lane >> 4, r16 = lane & 15;
    int sx0 = (q4 ^ (lane & 7)) * 8;
    int sx1 = ((q4 + 4) ^ (lane & 7)) * 8;
    int col = lane & 15;

    float delta = delta_p[0];
    float atv[4];
    _Float16 amh[4];
    #pragma unroll
    for (int nt = 0; nt < 4; nt++) {
        int node = n0 + nt * 16 + col;
        float logd = logf((float)deg[node] + 1.0f);
        amh[nt] = (_Float16)(logd / delta);
        atv[nt] = delta / fmaxf(logd, 1e-5f);
    }

    f32x4 acc[2][4], ac3[2][4];
    #pragma unroll
    for (int a = 0; a < 2; a++)
        #pragma unroll
        for (int b = 0; b < 4; b++) {
            acc[a][b] = (f32x4){0.f, 0.f, 0.f, 0.f};
            ac3[a][b] = (f32x4){0.f, 0.f, 0.f, 0.f};
        }

    for (int ki = 0; ki < 10; ki++) {
        int k0 = ki * 64;
        bool sreg = (k0 >= 128);
        __syncthreads();
        #pragma unroll
        for (int r = 0; r < 4; r++) {
            int rr = r * 4 + w;
            const _Float16* wrow = Wf + (size_t)(rr * 8 + srow8) * D_WROW;
            gll16(&A1[rr * 512], wrow + k0 + stg);
        }
        if (sreg) {
            #pragma unroll
            for (int r = 0; r < 4; r++) {
                int rr = r * 4 + w;
                const _Float16* wrow = Wf + (size_t)(rr * 8 + srow8) * D_WROW;
                gll16(&A2[rr * 512], wrow + 512 + k0 + stg);
                gll16(&A3[rr * 512], wrow + 1024 + k0 + stg);
            }
        }
        #pragma unroll
        for (int q = 0; q < 2; q++) {
            int rr = q * 4 + w;
            gll16(&Bt[rr * 512], Gf + (size_t)(n0 + rr * 8 + srow8) * D_G + k0 + stg);
        }
        __syncthreads();
        f16x8 a00 = *(const f16x8*)&A1[(w * 32 + r16) * 64 + sx0];
        f16x8 a01 = *(const f16x8*)&A1[(w * 32 + r16) * 64 + sx1];
        f16x8 a10 = *(const f16x8*)&A1[(w * 32 + 16 + r16) * 64 + sx0];
        f16x8 a11 = *(const f16x8*)&A1[(w * 32 + 16 + r16) * 64 + sx1];
        if (!sreg) {
            #pragma unroll
            for (int nt = 0; nt < 4; nt++) {
                f16x8 b0 = *(const f16x8*)&Bt[(nt * 16 + r16) * 64 + sx0];
                f16x8 b1 = *(const f16x8*)&Bt[(nt * 16 + r16) * 64 + sx1];
                acc[0][nt] = __builtin_amdgcn_mfma_f32_16x16x32_f16(a00, b0, acc[0][nt], 0, 0, 0);
                acc[1][nt] = __builtin_amdgcn_mfma_f32_16x16x32_f16(a10, b0, acc[1][nt], 0, 0, 0);
                acc[0][nt] = __builtin_amdgcn_mfma_f32_16x16x32_f16(a01, b1, acc[0][nt], 0, 0, 0);
                acc[1][nt] = __builtin_amdgcn_mfma_f32_16x16x32_f16(a11, b1, acc[1][nt], 0, 0, 0);
            }
        } else {
            f16x8 w2a0 = *(const f16x8*)&A2[(w * 32 + r16) * 64 + sx0];
            f16x8 w2a1 = *(const f16x8*)&A2[(w * 32 + r16) * 64 + sx1];
            f16x8 w2b0 = *(const f16x8*)&A2[(w * 32 + 16 + r16) * 64 + sx0];
            f16x8 w2b1 = *(const f16x8*)&A2[(w * 32 + 16 + r16) * 64 + sx1];
            f16x8 w3a0 = *(const f16x8*)&A3[(w * 32 + r16) * 64 + sx0];
            f16x8 w3a1 = *(const f16x8*)&A3[(w * 32 + r16) * 64 + sx1];
            f16x8 w3b0 = *(const f16x8*)&A3[(w * 32 + 16 + r16) * 64 + sx0];
            f16x8 w3b1 = *(const f16x8*)&A3[(w * 32 + 16 + r16) * 64 + sx1];
            #pragma unroll
            for (int nt = 0; nt < 4; nt++) {
                f16x8 b0 = *(const f16x8*)&Bt[(nt * 16 + r16) * 64 + sx0];
                f16x8 b1 = *(const f16x8*)&Bt[(nt * 16 + r16) * 64 + sx1];
                f16x8 bm0 = b0 * amh[nt];
                f16x8 bm1 = b1 * amh[nt];
                acc[0][nt] = __builtin_amdgcn_mfma_f32_16x16x32_f16(a00, b0, acc[0][nt], 0, 0, 0);
                acc[1][nt] = __builtin_amdgcn_mfma_f32_16x16x32_f16(a10, b0, acc[1][nt], 0, 0, 0);
                acc[0][nt] = __builtin_amdgcn_mfma_f32_16x16x32_f16(a01, b1, acc[0][nt], 0, 0, 0);
                acc[1][nt] = __builtin_amdgcn_mfma_f32_16x16x32_f16(a11, b1, acc[1][nt], 0, 0, 0);
                acc[0][nt] = __builtin_amdgcn_mfma_f32_16x16x32_f16(w2a0, bm0, acc[0][nt], 0, 0, 0);
                acc[1][nt] = __builtin_amdgcn_mfma_f32_16x16x32_f16(w2b0, bm0, acc[1][nt], 0, 0, 0);
                acc[0][nt] = __builtin_amdgcn_mfma_f32_16x16x32_f16(w2a1, bm1, acc[0][nt], 0, 0, 0);
                acc[1][nt] = __builtin_amdgcn_mfma_f32_16x16x32_f16(w2b1, bm1, acc[1][nt], 0, 0, 0);
                ac3[0][nt] = __builtin_amdgcn_mfma_f32_16x16x32_f16(w3a0, b0, ac3[0][nt], 0, 0, 0);
                ac3[1][nt] = __builtin_amdgcn_mfma_f32_16x16x32_f16(w3b0, b0, ac3[1][nt], 0, 0, 0);
                ac3[0][nt] = __builtin_amdgcn_mfma_f32_16x16x32_f16(w3a1, b1, ac3[0][nt], 0, 0, 0);
                ac3[1][nt] = __builtin_amdgcn_mfma_f32_16x16x32_f16(w3b1, b1, ac3[1][nt], 0, 0, 0);
            }
        }
    }
    // D[row=(lane>>4)*4+reg][col=lane&15]; row -> j, col -> node
    int rowq = q4 * 4;
    #pragma unroll
    for (int nt = 0; nt < 4; nt++) {
        int node = n0 + nt * 16 + col;
        float at = atv[nt];
        #pragma unroll
        for (int mt = 0; mt < 2; mt++) {
            int jb = w * 32 + mt * 16 + rowq;
            f32x4 v = acc[mt][nt], v3 = ac3[mt][nt];
            ushort4 o;
            o.x = f2h(fmaxf(v.x + at * v3.x + bias[jb], 0.0f));
            o.y = f2h(fmaxf(v.y + at * v3.y + bias[jb + 1], 0.0f));
            o.z = f2h(fmaxf(v.z + at * v3.z + bias[jb + 2], 0.0f));
            o.w = f2h(fmaxf(v.w + at * v3.w + bias[jb + 3], 0.0f));
            *(ushort4*)&hout[(size_t)node * D_HIDC + jb] = o;
        }
    }
}

// ---------------- epilogue kernels ----------------

__global__ void __launch_bounds__(256) k_pool(
        const u16* __restrict__ h, const int* __restrict__ goff,
        float* __restrict__ pooled) {
    __shared__ float sm[256];
    int g = blockIdx.x >> 2, s = blockIdx.x & 3;
    int gb = goff[g], ge = goff[g + 1];
    int len = ge - gb;
    int q = (len + 3) >> 2;
    int nb = gb + s * q;
    int ne = min(nb + q, ge);
    int t = threadIdx.x;
    int j = t & 127, half = t >> 7;
    float acc = 0.0f;
    for (int n = nb + half; n < ne; n += 2)
        acc += h2f(h[(size_t)n * D_HIDC + j]);
    sm[t] = acc; __syncthreads();
    if (t < 128) {
        float v = sm[t] + sm[t + 128];
        atomicAdd(&pooled[g * D_HIDC + j], v);
    }
}

// one block per graph; redundant mu/var recompute (pooled is tiny, L2-hot)
__global__ void __launch_bounds__(128) k_bn_fc(
        const float* __restrict__ pooled, const float* __restrict__ gamma,
        const float* __restrict__ beta, const float* __restrict__ fcW,
        const float* __restrict__ fcb, float* __restrict__ out) {
    __shared__ float bn[D_HIDC];
    int g = blockIdx.x, t = threadIdx.x;
    float s = 0.f, q = 0.f;
    for (int gg = 0; gg < N_GRAPHSC; gg++) {
        float v = pooled[gg * D_HIDC + t];
        s += v; q += v * v;
    }
    float mu = s * (1.0f / N_GRAPHSC);
    float var = q * (1.0f / N_GRAPHSC) - mu * mu;
    float inv = 1.0f / sqrtf(var + 1e-5f);
    bn[t] = (pooled[g * D_HIDC + t] - mu) * inv * gamma[t] + beta[t];
    __syncthreads();
    if (t < D_LATC) {
        float accum = fcb[t];
        for (int j = 0; j < D_HIDC; j++) accum += bn[j] * fcW[j * D_LATC + t];
        out[g * D_LATC + t] = accum;
    }
}

// ---------------- launch ----------------

extern "C" void kernel_launch(void* const* d_in, const int* in_sizes, int n_in,
                              void* d_out, int out_size, void* d_ws, size_t ws_size,
                              hipStream_t stream) {
    const float* x     = (const float*)d_in[0];
    const int*   ei    = (const int*)d_in[1];
    const int*   batch = (const int*)d_in[2];
    const float* W0 = (const float*)d_in[3];
    const float* b0 = (const float*)d_in[4];
    const float* W1 = (const float*)d_in[5];
    const float* b1 = (const float*)d_in[6];
    const float* W2 = (const float*)d_in[7];
    const float* b2 = (const float*)d_in[8];
    const float* gamma = (const float*)d_in[9];
    const float* beta  = (const float*)d_in[10];
    const float* fcW   = (const float*)d_in[11];
    const float* fcb   = (const float*)d_in[12];
    float* out = (float*)d_out;
    const int* srcv = ei;
    const int* dstv = ei + N_EDGESC;

    char* p = (char*)d_ws;
    auto alloc = [&](size_t bytes) -> char* {
        char* r = p;
        p += (bytes + 255) & ~(size_t)255;
        return r;
    };
    int*   deg_cnt = (int*)alloc((size_t)N_PAD * 4);
    int*   cursor  = (int*)alloc((size_t)N_NODESC * 4);
    float* delta_p = (float*)alloc(4);
    float* pooled  = (float*)alloc((size_t)N_GRAPHSC * D_HIDC * 4);
    char*  zero_end = p;
    int*   row_off = (int*)alloc((size_t)(N_NODESC + 1) * 4);
    int*   goff    = (int*)alloc((size_t)(N_GRAPHSC + 1) * 4);
    int*   bsum    = (int*)alloc(256 * 4);
    float* lsum    = (float*)alloc(256 * 4);
    int*   csr_src = (int*)alloc((size_t)N_EDGESC * 4);
    u16*   Wt      = (u16*)alloc((size_t)3 * D_WROW * D_HIDC * 2);   // 1.28 MB
    u16*   hA      = (u16*)alloc((size_t)N_PAD * D_HIDC * 2);        // 12.8 MB
    u16*   hB      = (u16*)alloc((size_t)N_PAD * D_HIDC * 2);        // 12.8 MB
    u16*   G       = (u16*)alloc((size_t)N_PAD * D_G * 2);           // 64.1 MB

    int nz = (int)((zero_end - (char*)deg_cnt) / 4);
    int ZB = (nz + 255) / 256;
    int setup_grid = ZB + 12500 + 2496 + 1;
    k_setup<<<setup_grid, 256, 0, stream>>>(x, W0, W1, W2, batch,
                                            hB, Wt, deg_cnt, nz, ZB, goff);
    k_count<<<(N_EDGESC + 255) / 256, 256, 0, stream>>>(dstv, deg_cnt);
    k_scan_part<<<196, 256, 0, stream>>>(deg_cnt, bsum, lsum);
    k_scan_block<<<1, 256, 0, stream>>>(bsum, lsum, delta_p);
    k_scan_final<<<196, 256, 0, stream>>>(deg_cnt, bsum, row_off);
    k_fill_csr<<<(N_EDGESC + 255) / 256, 256, 0, stream>>>(srcv, dstv, row_off, cursor, csr_src);

    const float* bs[3] = {b0, b1, b2};
    const u16* h_in[3]  = {hB, hA, hB};
    u16*       h_out[3] = {hA, hB, hA};
    size_t wsz = (size_t)D_WROW * D_HIDC;
    for (int l = 0; l < 3; l++) {
        k_aggregate<<<(N_NODESC + 3) / 4, 256, 0, stream>>>(
            h_in[l], row_off, csr_src, G);
        k_gemm<<<N_PAD / 64, 256, 0, stream>>>(
            G, Wt + (size_t)l * wsz, deg_cnt, delta_p, bs[l], h_out[l]);
    }
    k_pool<<<4 * N_GRAPHSC, 256, 0, stream>>>(h_out[2], goff, pooled);
    k_bn_fc<<<N_GRAPHSC, 128, 0, stream>>>(pooled, gamma, beta, fcW, fcb, out);
}